// Round 1
// baseline (435.060 us; speedup 1.0000x reference)
//
#include <hip/hip_runtime.h>
#include <hip/hip_fp16.h>

#define B_ 256
#define V_ 1000
#define P_ 200
#define L_ 50
#define H_ 384
#define H3_ 1152
#define NW_ 10
#define OUT1_OFF 12800000

typedef _Float16 half8 __attribute__((ext_vector_type(8)));
typedef float floatx4 __attribute__((ext_vector_type(4)));

// ---------------------------------------------------------------------------
// prep: f16 weight conversions, h0 init, S-coefficient init, gate softmax,
//       and output-1 (acts.T) write.
// ---------------------------------------------------------------------------
__global__ __launch_bounds__(256) void prep_kernel(
    const float* __restrict__ gate_emb, const float* __restrict__ prog_emb,
    const float* __restrict__ sk, const float* __restrict__ w_ih,
    const float* __restrict__ w_hh, const int* __restrict__ instr,
    const int* __restrict__ tacts,
    float* __restrict__ h0, float* __restrict__ S_buf, float* __restrict__ g01,
    _Float16* __restrict__ whh_h, _Float16* __restrict__ wih_h,
    _Float16* __restrict__ prog_h, float* __restrict__ out)
{
  const int stride = gridDim.x * blockDim.x;
  const int tid = blockIdx.x * blockDim.x + threadIdx.x;

  for (int i = tid; i < H3_*H_; i += stride) whh_h[i] = (_Float16)w_hh[i];
  for (int i = tid; i < H3_*224; i += stride) {
    int r = i / 224, c = i - r*224;
    wih_h[i] = (_Float16)(c < P_ ? w_ih[r*P_ + c] : 0.f);  // zero-pad K to 224
  }
  for (int i = tid; i < V_*P_; i += stride) prog_h[i] = (_Float16)prog_emb[i];
  for (int i = tid; i < B_*H_; i += stride) h0[i] = sk[(i % H_) & 127];
  for (int i = tid; i < B_*600; i += stride) S_buf[i] = ((i % 12) == 0) ? 1.f : 0.f;
  for (int i = tid; i < NW_*B_; i += stride) {
    int w = i / B_, b = i - w*B_;
    int word = instr[(1+w)*B_ + b];
    float e0 = gate_emb[word*2], e1 = gate_emb[word*2+1];
    float m = fmaxf(e0, e1);
    float a = __expf(e0-m), c = __expf(e1-m);
    float inv = 1.f/(a+c);
    g01[i*2] = a*inv; g01[i*2+1] = c*inv;
  }
  for (int i = tid; i < B_*L_; i += stride) {
    int b = i / L_, l = i - b*L_;
    out[OUT1_OFF + i] = (float)tacts[(1+l)*B_ + b];
  }
}

// ---------------------------------------------------------------------------
// gi_gemm: giv[v][n] = program_emb[v] @ w_ih.T + b_ih   (vocab-wide, once)
// M-tile 16 (vocab), per-wave N-tile 16 (block N=64), K padded 200->224.
// ---------------------------------------------------------------------------
__global__ __launch_bounds__(256) void gi_gemm(
    const _Float16* __restrict__ prog_h, const _Float16* __restrict__ wih_h,
    const float* __restrict__ b_ih, float* __restrict__ giv)
{
  __shared__ _Float16 pA[16][232];
  const int tid = threadIdx.x;
  const int v0 = blockIdx.x * 16;
  const int n0 = blockIdx.y * 64;

  for (int i = tid; i < 16*224; i += 256) {
    int r = i / 224, c = i - r*224;
    int v = v0 + r;
    _Float16 val = (_Float16)0.f;
    if (v < V_ && c < P_) val = prog_h[v*P_ + c];
    pA[r][c] = val;
  }
  __syncthreads();

  const int wave = tid >> 6, lane = tid & 63;
  const int m = lane & 15, kg = lane >> 4;
  const int n_t = n0 + wave*16;
  floatx4 acc = {0.f, 0.f, 0.f, 0.f};
  #pragma unroll
  for (int ks = 0; ks < 7; ++ks) {
    const int kk = ks*32 + kg*8;
    half8 av = *(const half8*)&pA[m][kk];
    half8 bv = *(const half8*)&wih_h[(n_t + m)*224 + kk];
    acc = __builtin_amdgcn_mfma_f32_16x16x32_f16(av, bv, acc, 0, 0, 0);
  }
  const int nn = n_t + (lane & 15);
  const float bias = b_ih[nn];
  #pragma unroll
  for (int r = 0; r < 4; ++r) {
    int mm = v0 + kg*4 + r;
    if (mm < V_) giv[(size_t)mm*H3_ + nn] = acc[r] + bias;
  }
}

// ---------------------------------------------------------------------------
// step: one recurrence step. Block = (batch-group of 16) x (24 h-outputs).
// Waves 0-3: MFMA GEMM gh = h @ w_hh_slice.T.  Wave 4: read-attn + rv/nv.
// Wave 5: write-mask.  Then S-coefficient update + GRU gate epilogue.
// ---------------------------------------------------------------------------
__global__ __launch_bounds__(512) void step_kernel(
    const float* __restrict__ h_cur, float* __restrict__ h_nxt,
    float* __restrict__ S_buf,
    const _Float16* __restrict__ whh_h, const float* __restrict__ giv,
    const float* __restrict__ g01, const float* __restrict__ keys,
    const float* __restrict__ b_hh, const int* __restrict__ instr, int widx)
{
  __shared__ _Float16 hT[16][392];   // f16 h tile (pad 8)
  __shared__ float ghT[16][80];      // GEMM result (cols 0..71 valid)
  __shared__ float wmm[50];
  __shared__ float nv[11];
  __shared__ float Srow[50][12];
  __shared__ int   wordid[16];
  __shared__ float g0s[16], g1s[16];

  const int bid   = blockIdx.x;
  const int slice = bid & 15;
  const int b0    = (bid >> 4) << 4;
  const int b_own = bid;             // == b0 + slice
  const int k0    = slice * 24;
  const int tid   = threadIdx.x;

  for (int i = tid; i < 16*H_; i += 512) {
    int bl = i / H_, k = i - bl*H_;
    hT[bl][k] = (_Float16)h_cur[(b0+bl)*H_ + k];
  }
  for (int i = tid; i < 600; i += 512) Srow[i/12][i%12] = S_buf[b_own*600 + i];
  if (tid < 16) {
    wordid[tid] = instr[(1+widx)*B_ + b0 + tid];
    g0s[tid] = g01[(widx*B_ + b0 + tid)*2 + 0];
    g1s[tid] = g01[(widx*B_ + b0 + tid)*2 + 1];
  }
  __syncthreads();

  const int wave = tid >> 6;
  const int lane = tid & 63;

  if (wave < 4) {
    const int m  = lane & 15;
    const int kg = lane >> 4;
    for (int nt = wave; nt < 5; nt += 4) {
      const int ncol = nt*16 + m;
      const int ncl  = ncol < 72 ? ncol : 71;
      const int row  = (ncl/24)*H_ + k0 + (ncl % 24);
      const _Float16* __restrict__ wrow = whh_h + (size_t)row*H_;
      floatx4 acc = {0.f, 0.f, 0.f, 0.f};
      #pragma unroll
      for (int ks = 0; ks < 12; ++ks) {
        const int kk = ks*32 + kg*8;
        half8 av = *(const half8*)&hT[m][kk];
        half8 bv = *(const half8*)&wrow[kk];
        acc = __builtin_amdgcn_mfma_f32_16x16x32_f16(av, bv, acc, 0, 0, 0);
      }
      if (ncol < 72) {
        #pragma unroll
        for (int r = 0; r < 4; ++r) ghT[kg*4 + r][ncol] = acc[r];
      }
    }
  } else if (wave < 6) {
    // wave 4: read_p (h[128:256]) -> read_attn -> rv/nv ; wave 5: write_p -> wm
    const float* __restrict__ hp = h_cur + (size_t)b_own*H_ + (wave == 4 ? 128 : 256);
    float val = 0.f;
    if (lane < 50) {
      const float4* __restrict__ hp4 = (const float4*)hp;
      const float4* __restrict__ kr4 = (const float4*)(keys + lane*128);
      float s0=0.f, s1=0.f, s2=0.f, s3=0.f;
      #pragma unroll
      for (int k = 0; k < 32; ++k) {
        float4 a = hp4[k], bq = kr4[k];
        s0 += a.x*bq.x; s1 += a.y*bq.y; s2 += a.z*bq.z; s3 += a.w*bq.w;
      }
      val = (s0+s1)+(s2+s3);
    }
    float mx = lane < 50 ? val : -1e30f;
    #pragma unroll
    for (int off = 32; off; off >>= 1) mx = fmaxf(mx, __shfl_xor(mx, off));
    float e = lane < 50 ? __expf(val - mx) : 0.f;
    float sm = e;
    #pragma unroll
    for (int off = 32; off; off >>= 1) sm += __shfl_xor(sm, off);
    float p = e / sm;
    if (wave == 5) {
      if (lane < 50) wmm[lane] = p;
    } else {
      const int jj = lane < 12 ? lane : 0;
      float rv = 0.f;
      for (int l = 0; l < 50; ++l) {
        float pl = __shfl(p, l);
        rv += pl * Srow[l][jj];
      }
      if (lane < 11) {
        nv[lane] = g1s[slice]*rv + (lane == (1+widx) ? g0s[slice] : 0.f);
      }
    }
  }
  __syncthreads();

  // S-coefficient update for owned batch element
  for (int i = tid; i < 550; i += 512) {
    const int l = i / 11, j = i - l*11;
    const float wv = wmm[l];
    S_buf[b_own*600 + l*12 + j] = wv*nv[j] + (1.f - wv)*Srow[l][j];
  }

  // GRU gate epilogue + word-gated h update (16 b x 24 outputs)
  for (int i = tid; i < 384; i += 512) {
    const int bl = i / 24, k = i - bl*24;
    const int kk = k0 + k;
    const float gh0 = ghT[bl][k]    + b_hh[kk];
    const float gh1 = ghT[bl][24+k] + b_hh[384+kk];
    const float gh2 = ghT[bl][48+k] + b_hh[768+kk];
    const float* __restrict__ gi = giv + (size_t)wordid[bl]*H3_ + kk;
    const float r  = 1.f/(1.f + __expf(-(gi[0]   + gh0)));
    const float z  = 1.f/(1.f + __expf(-(gi[384] + gh1)));
    const float x2 = gi[768] + r*gh2;
    const float nn = 2.f/(1.f + __expf(-2.f*x2)) - 1.f;   // tanh
    const float hold = h_cur[(b0+bl)*H_ + kk];
    const float hnew = (1.f - z)*nn + z*hold;
    h_nxt[(b0+bl)*H_ + kk] = g0s[bl]*hold + g1s[bl]*hnew;
  }
}

// ---------------------------------------------------------------------------
// epilogue: sv[b,l,v] = S[b,l,0]*init_value[v] + sum_w S[b,l,1+w]*prim[word_w][v]
// then log_softmax over v, written transposed out[b][v][l] (coalesced via LDS).
// ---------------------------------------------------------------------------
__global__ __launch_bounds__(256) void epilogue_kernel(
    const float* __restrict__ S_buf, const float* __restrict__ prim_emb,
    const float* __restrict__ iv_g, const int* __restrict__ instr,
    float* __restrict__ out)
{
  __shared__ float prim[10][1000];
  __shared__ float Sr[50][12];
  __shared__ float iv[1000];
  __shared__ float ls[50];
  __shared__ float tile[64][51];

  const int b = blockIdx.x;
  const int tid = threadIdx.x;

  for (int wi = 0; wi < 10; ++wi) {
    int word = instr[(1+wi)*B_ + b];
    for (int i = tid; i < V_; i += 256) prim[wi][i] = prim_emb[(size_t)word*V_ + i];
  }
  for (int i = tid; i < V_;  i += 256) iv[i] = iv_g[i];
  for (int i = tid; i < 600; i += 256) Sr[i/12][i%12] = S_buf[b*600 + i];
  __syncthreads();

  const int wave = tid >> 6, lane = tid & 63;

  // phase A: per-row log-sum-exp (one wave per l)
  for (int l = wave; l < L_; l += 4) {
    float s0 = Sr[l][0];
    float cw[10];
    #pragma unroll
    for (int wi = 0; wi < 10; ++wi) cw[wi] = Sr[l][1+wi];
    float sv[16];
    float mx = -1e30f;
    #pragma unroll
    for (int j = 0; j < 16; ++j) {
      int v = lane + 64*j;
      float s = -1e30f;
      if (v < V_) {
        s = s0 * iv[v];
        #pragma unroll
        for (int wi = 0; wi < 10; ++wi) s += cw[wi]*prim[wi][v];
      }
      sv[j] = s;
      mx = fmaxf(mx, s);
    }
    #pragma unroll
    for (int off = 32; off; off >>= 1) mx = fmaxf(mx, __shfl_xor(mx, off));
    float se = 0.f;
    #pragma unroll
    for (int j = 0; j < 16; ++j) {
      int v = lane + 64*j;
      if (v < V_) se += __expf(sv[j] - mx);
    }
    #pragma unroll
    for (int off = 32; off; off >>= 1) se += __shfl_xor(se, off);
    if (lane == 0) ls[l] = mx + __logf(se);
  }
  __syncthreads();

  // phase B: recompute sv per 64-v chunk into LDS tile, write coalesced
  for (int c = 0; c < 16; ++c) {
    const int v0 = c*64;
    const int v  = v0 + lane;
    const bool ok = v < V_;
    for (int l = wave; l < L_; l += 4) {
      float s = 0.f;
      if (ok) {
        s = Sr[l][0]*iv[v];
        #pragma unroll
        for (int wi = 0; wi < 10; ++wi) s += Sr[l][1+wi]*prim[wi][v];
        s -= ls[l];
      }
      tile[lane][l] = s;
    }
    __syncthreads();
    const int nvalid = (V_ - v0) < 64 ? (V_ - v0) : 64;
    const int cnt = nvalid * L_;
    for (int f = tid; f < cnt; f += 256) {
      int vl = f / L_, l = f - vl*L_;
      out[(size_t)b*50000 + (size_t)(v0+vl)*50 + l] = tile[vl][l];
    }
    __syncthreads();
  }
}

// ---------------------------------------------------------------------------
extern "C" void kernel_launch(void* const* d_in, const int* in_sizes, int n_in,
                              void* d_out, int out_size, void* d_ws, size_t ws_size,
                              hipStream_t stream)
{
  (void)in_sizes; (void)n_in; (void)out_size; (void)ws_size;
  const float* gate_emb = (const float*)d_in[0];
  const float* prog_emb = (const float*)d_in[1];
  const float* prim_emb = (const float*)d_in[2];
  const float* sk       = (const float*)d_in[3];
  const float* iv       = (const float*)d_in[4];
  const float* w_ih     = (const float*)d_in[5];
  const float* w_hh     = (const float*)d_in[6];
  const float* b_ih     = (const float*)d_in[7];
  const float* b_hh     = (const float*)d_in[8];
  const int*   instr    = (const int*)d_in[9];
  const int*   tacts    = (const int*)d_in[10];
  float* out = (float*)d_out;

  float* ws    = (float*)d_ws;
  float* h_buf = ws;                       // 2*256*384 f32
  float* S_buf = h_buf + 2*B_*H_;          // 256*600 f32
  float* g01   = S_buf + B_*600;           // 5120 f32
  float* giv   = g01 + NW_*B_*2;           // 1000*1152 f32
  _Float16* whh_h  = (_Float16*)(giv + (size_t)V_*H3_);
  _Float16* wih_h  = whh_h + (size_t)H3_*H_;
  _Float16* prog_h = wih_h + (size_t)H3_*224;

  hipLaunchKernelGGL(prep_kernel, dim3(1024), dim3(256), 0, stream,
      gate_emb, prog_emb, sk, w_ih, w_hh, instr, tacts,
      h_buf, S_buf, g01, whh_h, wih_h, prog_h, out);

  hipLaunchKernelGGL(gi_gemm, dim3(63, 18), dim3(256), 0, stream,
      prog_h, wih_h, b_ih, giv);

  for (int t = 0; t < 30; ++t) {
    const float* hc = h_buf + (size_t)(t & 1)*(B_*H_);
    float*       hn = h_buf + (size_t)((t+1) & 1)*(B_*H_);
    hipLaunchKernelGGL(step_kernel, dim3(256), dim3(512), 0, stream,
        hc, hn, S_buf, whh_h, giv, g01, sk, b_hh, instr, t/3);
  }

  hipLaunchKernelGGL(epilogue_kernel, dim3(256), dim3(256), 0, stream,
      S_buf, prim_emb, iv, instr, out);
}